// Round 17
// baseline (1046.959 us; speedup 1.0000x reference)
//
#include <hip/hip_runtime.h>
#include <cstdint>

#define B_ 64
#define N_ 4096
#define D_ 256
#define NS_ 8
#define HID_ 512
#define TOK_ 128
#define EPS_ 1e-8f
#define SCALE_ 0.0625f
#define LN_EPS_ 1e-5f

typedef _Float16 f16;
typedef __attribute__((ext_vector_type(4))) _Float16 f16x4;
typedef __attribute__((ext_vector_type(8))) _Float16 f16x8;
typedef __attribute__((ext_vector_type(4))) float f32x4;

#define MFMA16(a, b, c) __builtin_amdgcn_mfma_f32_16x16x32_f16(a, b, c, 0, 0, 0)

// ---------------- merged setup: xh LN-cast | WkX | GRU-wT cast | slots | w1/w2 cast ----
__global__ __launch_bounds__(256) void k_setup(
    const float* __restrict__ in, const float* __restrict__ gin,
    const float* __restrict__ bin, f16* __restrict__ xh,
    const float* __restrict__ Wk, float* __restrict__ WkX,
    const float* __restrict__ wi, const float* __restrict__ wh,
    f16* __restrict__ wiTh, f16* __restrict__ whTh,
    const float* __restrict__ noise, const float* __restrict__ mu,
    const float* __restrict__ ls, float* __restrict__ slots,
    const float* __restrict__ w1, const float* __restrict__ w2,
    f16* __restrict__ w1h, f16* __restrict__ w2h) {
  const int blk = blockIdx.x;
  const int t = threadIdx.x;
  if (blk < 65536) {
    const int wave = t >> 6, lane = t & 63;
    const size_t row = (size_t)blk * 4 + wave;
    const float* r = in + row * D_;
    float4 a = *(const float4*)(r + lane * 4);
    float s1 = a.x + a.y + a.z + a.w;
    float s2 = a.x * a.x + a.y * a.y + a.z * a.z + a.w * a.w;
    #pragma unroll
    for (int m = 32; m >= 1; m >>= 1) { s1 += __shfl_xor(s1, m, 64); s2 += __shfl_xor(s2, m, 64); }
    const float mean = s1 * (1.f / D_);
    const float rstd = rsqrtf(s2 * (1.f / D_) - mean * mean + LN_EPS_);
    float4 gg = *(const float4*)(gin + lane * 4);
    float4 bv = *(const float4*)(bin + lane * 4);
    f16x4 o;
    o[0] = (f16)((a.x - mean) * rstd * gg.x + bv.x);
    o[1] = (f16)((a.y - mean) * rstd * gg.y + bv.y);
    o[2] = (f16)((a.z - mean) * rstd * gg.z + bv.z);
    o[3] = (f16)((a.w - mean) * rstd * gg.w + bv.w);
    *(f16x4*)(xh + row * D_ + lane * 4) = o;
  } else if (blk < 65792) {
    const int e = blk - 65536;
    WkX[t * 256 + e] = Wk[e * 256 + t];
  } else if (blk < 66560) {
    const int idx = (blk - 65792) * 256 + t;
    const int o = idx >> 8, d = idx & 255;
    wiTh[d * 768 + o] = (f16)wi[idx];
    whTh[d * 768 + o] = (f16)wh[idx];
  } else if (blk < 67072) {
    const int idx = (blk - 66560) * 256 + t;
    const int d = idx & 255;
    slots[idx] = mu[d] + __expf(ls[d]) * noise[idx];
  } else if (blk < 67584) {
    const int idx = (blk - 67072) * 256 + t;
    w1h[idx] = (f16)w1[idx];
  } else {
    const int idx = (blk - 67584) * 256 + t;
    w2h[idx] = (f16)w2[idx];
  }
}

// ---------------- M[c][e] = SCALE * sum_d Wq[c][d] * WkX[d][e] ----------------
__global__ __launch_bounds__(256) void k_m(const float* __restrict__ Wq,
                                           const float* __restrict__ WkX,
                                           float* __restrict__ M) {
  __shared__ float wq[256];
  const int c = blockIdx.x, e = threadIdx.x;
  wq[e] = Wq[c * 256 + e];
  __syncthreads();
  float a0 = 0.f, a1 = 0.f, a2 = 0.f, a3 = 0.f;
  #pragma unroll 8
  for (int d = 0; d < 256; d += 4) {
    a0 = fmaf(wq[d],     WkX[(d)     * 256 + e], a0);
    a1 = fmaf(wq[d + 1], WkX[(d + 1) * 256 + e], a1);
    a2 = fmaf(wq[d + 2], WkX[(d + 2) * 256 + e], a2);
    a3 = fmaf(wq[d + 3], WkX[(d + 3) * 256 + e], a3);
  }
  M[c * 256 + e] = (a0 + a1 + a2 + a3) * SCALE_;
}

// ---------------- qkh = f16( LN(slots) @ M ) + zero ur/asum (once) ----------------
__global__ __launch_bounds__(256) void k_qk(const float* __restrict__ slots,
    const float* __restrict__ g, const float* __restrict__ b,
    const float* __restrict__ M, f16* __restrict__ qkh,
    float* __restrict__ ur, float* __restrict__ asum) {
  const int row = blockIdx.x;
  const int t = threadIdx.x;
  ur[(size_t)row * D_ + t] = 0.f;
  if (t == 0) asum[row] = 0.f;
  __shared__ float sl[256];
  __shared__ float red1[4], red2[4];
  float val = slots[(size_t)row * D_ + t];
  float s1 = val, s2 = val * val;
  #pragma unroll
  for (int m = 32; m >= 1; m >>= 1) { s1 += __shfl_xor(s1, m, 64); s2 += __shfl_xor(s2, m, 64); }
  int wave = t >> 6, lane = t & 63;
  if (lane == 0) { red1[wave] = s1; red2[wave] = s2; }
  __syncthreads();
  s1 = red1[0] + red1[1] + red1[2] + red1[3];
  s2 = red2[0] + red2[1] + red2[2] + red2[3];
  float mean = s1 * (1.f / D_);
  float rstd = rsqrtf(s2 * (1.f / D_) - mean * mean + LN_EPS_);
  sl[t] = (val - mean) * rstd * g[t] + b[t];
  __syncthreads();
  float a0 = 0.f, a1 = 0.f, a2 = 0.f, a3 = 0.f;
  #pragma unroll 8
  for (int d = 0; d < D_; d += 4) {
    a0 = fmaf(sl[d],     M[(d)     * D_ + t], a0);
    a1 = fmaf(sl[d + 1], M[(d + 1) * D_ + t], a1);
    a2 = fmaf(sl[d + 2], M[(d + 2) * D_ + t], a2);
    a3 = fmaf(sl[d + 3], M[(d + 3) * D_ + t], a3);
  }
  qkh[((size_t)(row >> 3) * 16 + (row & 7)) * D_ + t] = (f16)(a0 + a1 + a2 + a3);
}

// ---------------- MFMA attention, 512 thr (8 waves), TOK_=128 ----------------
// Phase A: one 16-token N-tile per wave (MFMA). Phase B: one slot per wave.
__global__ __launch_bounds__(512) void k_attn_upd(
    const f16* __restrict__ xh, const f16* __restrict__ qkh,
    float* __restrict__ ur, float* __restrict__ asum) {
  __shared__ __align__(16) f16 xt[TOK_ * 256];   // 64 KB, chunk-swizzled
  __shared__ __align__(16) f16 qs[16 * 256];     // 8 KB (rows 8-15 pad)
  __shared__ float wv_s[TOK_ * 12];              // 6 KB
  const int b = blockIdx.y;
  const int jt = blockIdx.x * TOK_;
  const int tid = threadIdx.x;
  const int wave = tid >> 6, lane = tid & 63;

  // stage qs: one f16x8 chunk per thread (16 rows x 32 chunks = 512)
  {
    const int r = tid >> 5, c = tid & 31;
    const f16* src = qkh + ((size_t)b * 16 + r) * D_;
    *(f16x8*)&qs[r * 256 + (c ^ (r & 7)) * 8] = *(const f16x8*)(src + c * 8);
  }
  // stage xt: 8 rounds x 8KB, coalesced loads, swizzled ds_write
  {
    const f16* src = xh + ((size_t)b * N_ + jt) * D_;
    f16x8 v[8];
    #pragma unroll
    for (int i = 0; i < 8; ++i) {
      const int r = i * 16 + (tid >> 5), c = tid & 31;
      v[i] = *(const f16x8*)(src + r * 256 + c * 8);
    }
    #pragma unroll
    for (int i = 0; i < 8; ++i) {
      const int r = i * 16 + (tid >> 5), c = tid & 31;
      *(f16x8*)&xt[r * 256 + (c ^ (r & 7)) * 8] = v[i];
    }
  }
  __syncthreads();

  // phase A: MFMA dots; A-frags (qk) loaded once; one N-tile per wave
  const int kg = lane >> 4;
  f16x8 afr[8];
  {
    const int arow = lane & 15;
    #pragma unroll
    for (int kk = 0; kk < 8; ++kk)
      afr[kk] = *(const f16x8*)&qs[arow * 256 + ((kk * 4 + kg) ^ (arow & 7)) * 8];
  }
  {
    const int tok = wave * 16 + (lane & 15);
    f32x4 acc = {0.f, 0.f, 0.f, 0.f};
    #pragma unroll
    for (int kk = 0; kk < 8; ++kk) {
      f16x8 bf = *(const f16x8*)&xt[tok * 256 + ((kk * 4 + kg) ^ (tok & 7)) * 8];
      acc = MFMA16(afr[kk], bf, acc);
    }
    float o0 = __shfl_xor(acc[0], 16, 64);
    float o1 = __shfl_xor(acc[1], 16, 64);
    float o2 = __shfl_xor(acc[2], 16, 64);
    float o3 = __shfl_xor(acc[3], 16, 64);
    if (lane < 32) {
      float m = fmaxf(fmaxf(fmaxf(acc[0], acc[1]), fmaxf(acc[2], acc[3])),
                      fmaxf(fmaxf(o0, o1), fmaxf(o2, o3)));
      float e0 = __expf(acc[0] - m), e1 = __expf(acc[1] - m);
      float e2 = __expf(acc[2] - m), e3 = __expf(acc[3] - m);
      float sm = e0 + e1 + e2 + e3;
      float so = __shfl_xor(sm, 16, 64);
      float inv = 1.f / (sm + so);
      float4 wv;
      wv.x = e0 * inv + EPS_; wv.y = e1 * inv + EPS_;
      wv.z = e2 * inv + EPS_; wv.w = e3 * inv + EPS_;
      *(float4*)&wv_s[tok * 12 + (lane >> 4) * 4] = wv;
      float r0 = wv.x, r1 = wv.y, r2 = wv.z, r3 = wv.w;
      #pragma unroll
      for (int mm = 1; mm <= 8; mm <<= 1) {
        r0 += __shfl_xor(r0, mm, 64); r1 += __shfl_xor(r1, mm, 64);
        r2 += __shfl_xor(r2, mm, 64); r3 += __shfl_xor(r3, mm, 64);
      }
      if ((lane & 15) == 0) {
        const int sb = (lane >> 4) * 4;
        atomicAdd(&asum[b * NS_ + sb + 0], r0);
        atomicAdd(&asum[b * NS_ + sb + 1], r1);
        atomicAdd(&asum[b * NS_ + sb + 2], r2);
        atomicAdd(&asum[b * NS_ + sb + 3], r3);
      }
    }
  }
  __syncthreads();

  // phase B: wave -> slot `wave`; lane -> d-quad; read LDS tile
  {
    const int ch0 = lane >> 1, sub = (lane & 1) * 4;
    float a0[4] = {0.f, 0.f, 0.f, 0.f};
    #pragma unroll 4
    for (int j = 0; j < TOK_; ++j) {
      f16x4 v = *(const f16x4*)&xt[j * 256 + (ch0 ^ (j & 7)) * 8 + sub];
      float w0 = wv_s[j * 12 + wave];
      a0[0] = fmaf(w0, (float)v[0], a0[0]);
      a0[1] = fmaf(w0, (float)v[1], a0[1]);
      a0[2] = fmaf(w0, (float)v[2], a0[2]);
      a0[3] = fmaf(w0, (float)v[3], a0[3]);
    }
    float* u0 = ur + ((size_t)b * NS_ + wave) * D_ + lane * 4;
    #pragma unroll
    for (int c = 0; c < 4; ++c) atomicAdd(u0 + c, a0[c]);
  }
}

// ---------------- GRU + LN + MLP + next-qk, ONE row per block, f16 weights ----------------
__global__ __launch_bounds__(256) void k_gru_mlp(
    float* __restrict__ ur, float* __restrict__ asum,
    const float* __restrict__ slots, const float* __restrict__ Wv,
    const f16* __restrict__ wiTh, const f16* __restrict__ whTh,
    const float* __restrict__ bi, const float* __restrict__ bh,
    const f16* __restrict__ w1h, const float* __restrict__ b1,
    const f16* __restrict__ w2h, const float* __restrict__ b2,
    const float* __restrict__ gf, const float* __restrict__ bf,
    const float* __restrict__ gs, const float* __restrict__ bs,
    const float* __restrict__ M,
    float* __restrict__ out, f16* __restrict__ qkh) {
  const int row = blockIdx.x;
  const int t = threadIdx.x;
  __shared__ float urs[256], xs[256], hs[256], ffs[256], hid[512];
  __shared__ float red1[4], red2[4];
  const int wave = t >> 6, lane = t & 63;
  const float hv = slots[(size_t)row * D_ + t];
  const float asv = asum[row];
  urs[t] = ur[(size_t)row * D_ + t];
  ur[(size_t)row * D_ + t] = 0.f;
  hs[t] = hv;
  __syncthreads();
  if (t == 0) asum[row] = 0.f;
  {
    const float ia = 1.f / asv;
    float u0 = 0.f, u1 = 0.f, u2 = 0.f, u3 = 0.f;
    #pragma unroll 8
    for (int e = 0; e < D_; e += 4) {
      u0 = fmaf(urs[e],     Wv[(size_t)(e)     * D_ + t], u0);
      u1 = fmaf(urs[e + 1], Wv[(size_t)(e + 1) * D_ + t], u1);
      u2 = fmaf(urs[e + 2], Wv[(size_t)(e + 2) * D_ + t], u2);
      u3 = fmaf(urs[e + 3], Wv[(size_t)(e + 3) * D_ + t], u3);
    }
    xs[t] = (u0 + u1 + u2 + u3) * ia;
  }
  __syncthreads();
  float gi0 = bi[t], gi1 = bi[D_ + t], gi2 = bi[2 * D_ + t];
  float gh0 = bh[t], gh1 = bh[D_ + t], gh2 = bh[2 * D_ + t];
  #pragma unroll 8
  for (int d = 0; d < D_; ++d) {
    const f16* wid = wiTh + d * 768;
    const f16* whd = whTh + d * 768;
    float xd = xs[d], hd = hs[d];
    gi0 = fmaf(xd, (float)wid[t], gi0);
    gi1 = fmaf(xd, (float)wid[D_ + t], gi1);
    gi2 = fmaf(xd, (float)wid[2 * D_ + t], gi2);
    gh0 = fmaf(hd, (float)whd[t], gh0);
    gh1 = fmaf(hd, (float)whd[D_ + t], gh1);
    gh2 = fmaf(hd, (float)whd[2 * D_ + t], gh2);
  }
  float r = 1.f / (1.f + __expf(-(gi0 + gh0)));
  float z = 1.f / (1.f + __expf(-(gi1 + gh1)));
  float n = tanhf(gi2 + r * gh2);
  float hnew = (1.f - z) * n + z * hv;
  float s1 = hnew, s2 = hnew * hnew;
  #pragma unroll
  for (int m = 32; m >= 1; m >>= 1) { s1 += __shfl_xor(s1, m, 64); s2 += __shfl_xor(s2, m, 64); }
  if (lane == 0) { red1[wave] = s1; red2[wave] = s2; }
  __syncthreads();
  s1 = red1[0] + red1[1] + red1[2] + red1[3];
  s2 = red2[0] + red2[1] + red2[2] + red2[3];
  float mean = s1 * (1.f / D_);
  float rstd = rsqrtf(s2 * (1.f / D_) - mean * mean + LN_EPS_);
  ffs[t] = (hnew - mean) * rstd * gf[t] + bf[t];
  __syncthreads();
  {
    float h1a = b1[t], h2a = b1[D_ + t], h1b = 0.f, h2b = 0.f;
    #pragma unroll 8
    for (int d = 0; d < D_; d += 2) {
      float f0 = ffs[d], f1 = ffs[d + 1];
      h1a = fmaf(f0, (float)w1h[(size_t)(d)     * HID_ + t],      h1a);
      h2a = fmaf(f0, (float)w1h[(size_t)(d)     * HID_ + D_ + t], h2a);
      h1b = fmaf(f1, (float)w1h[(size_t)(d + 1) * HID_ + t],      h1b);
      h2b = fmaf(f1, (float)w1h[(size_t)(d + 1) * HID_ + D_ + t], h2b);
    }
    hid[t] = fmaxf(h1a + h1b, 0.f); hid[D_ + t] = fmaxf(h2a + h2b, 0.f);
  }
  __syncthreads();
  float o;
  {
    float oa = b2[t], ob = 0.f;
    #pragma unroll 8
    for (int d = 0; d < HID_; d += 2) {
      oa = fmaf(hid[d],     (float)w2h[(size_t)(d)     * D_ + t], oa);
      ob = fmaf(hid[d + 1], (float)w2h[(size_t)(d + 1) * D_ + t], ob);
    }
    o = oa + ob + hnew;
  }
  out[(size_t)row * D_ + t] = o;
  // next-iteration qkh = f16( LN_s(new slots) @ M )
  s1 = o; s2 = o * o;
  #pragma unroll
  for (int m = 32; m >= 1; m >>= 1) { s1 += __shfl_xor(s1, m, 64); s2 += __shfl_xor(s2, m, 64); }
  __syncthreads();
  if (lane == 0) { red1[wave] = s1; red2[wave] = s2; }
  __syncthreads();
  s1 = red1[0] + red1[1] + red1[2] + red1[3];
  s2 = red2[0] + red2[1] + red2[2] + red2[3];
  mean = s1 * (1.f / D_);
  rstd = rsqrtf(s2 * (1.f / D_) - mean * mean + LN_EPS_);
  ffs[t] = (o - mean) * rstd * gs[t] + bs[t];
  __syncthreads();
  {
    float a0 = 0.f, a1 = 0.f, a2 = 0.f, a3 = 0.f;
    #pragma unroll 8
    for (int d = 0; d < D_; d += 4) {
      a0 = fmaf(ffs[d],     M[(d)     * D_ + t], a0);
      a1 = fmaf(ffs[d + 1], M[(d + 1) * D_ + t], a1);
      a2 = fmaf(ffs[d + 2], M[(d + 2) * D_ + t], a2);
      a3 = fmaf(ffs[d + 3], M[(d + 3) * D_ + t], a3);
    }
    qkh[((size_t)(row >> 3) * 16 + (row & 7)) * D_ + t] = (f16)(a0 + a1 + a2 + a3);
  }
}

extern "C" void kernel_launch(void* const* d_in, const int* in_sizes, int n_in,
                              void* d_out, int out_size, void* d_ws, size_t ws_size,
                              hipStream_t stream) {
  (void)in_sizes; (void)n_in; (void)out_size; (void)ws_size;
  const float* inputs = (const float*)d_in[0];
  const float* noise  = (const float*)d_in[1];
  const float* mu     = (const float*)d_in[2];
  const float* ls     = (const float*)d_in[3];
  const float* Wq     = (const float*)d_in[4];
  const float* Wk     = (const float*)d_in[5];
  const float* Wv     = (const float*)d_in[6];
  const float* gwi    = (const float*)d_in[7];
  const float* gwh    = (const float*)d_in[8];
  const float* gbi    = (const float*)d_in[9];
  const float* gbh    = (const float*)d_in[10];
  const float* w1     = (const float*)d_in[11];
  const float* b1     = (const float*)d_in[12];
  const float* w2     = (const float*)d_in[13];
  const float* b2     = (const float*)d_in[14];
  const float* gin    = (const float*)d_in[15];
  const float* bin    = (const float*)d_in[16];
  const float* gs     = (const float*)d_in[17];
  const float* bs     = (const float*)d_in[18];
  const float* gff    = (const float*)d_in[19];
  const float* bff    = (const float*)d_in[20];

  // workspace layout
  const size_t KV = (size_t)B_ * N_ * D_;
  f16*   xh    = (f16*)d_ws;                       // 134 MB
  float* slots = (float*)(xh + KV);
  f16*   qkh   = (f16*)(slots + 131072);
  float* asum  = (float*)(qkh + 262144);
  float* ur    = asum + 512;
  float* WkX   = ur + 131072;
  float* M     = WkX + 65536;
  f16*   wiTh  = (f16*)(M + 65536);
  f16*   whTh  = wiTh + 196608;
  f16*   w1h   = whTh + 196608;
  f16*   w2h   = w1h + 131072;

  k_setup<<<68096, 256, 0, stream>>>(inputs, gin, bin, xh, Wk, WkX,
                                     gwi, gwh, wiTh, whTh,
                                     noise, mu, ls, slots, w1, w2, w1h, w2h);
  k_m<<<256, 256, 0, stream>>>(Wq, WkX, M);
  k_qk<<<512, 256, 0, stream>>>(slots, gs, bs, M, qkh, ur, asum);
  for (int it = 0; it < 4; ++it) {
    k_attn_upd<<<dim3(N_ / TOK_, B_), 512, 0, stream>>>(xh, qkh, ur, asum);
    float* outp = (it == 3) ? (float*)d_out : slots;
    k_gru_mlp<<<512, 256, 0, stream>>>(ur, asum, slots, Wv, wiTh, whTh, gbi, gbh,
                                       w1h, b1, w2h, b2, gff, bff, gs, bs, M,
                                       outp, qkh);
  }
}

// Round 18
// 488.224 us; speedup vs baseline: 2.1444x; 2.1444x over previous
//
#include <hip/hip_runtime.h>
#include <cstdint>

#define B_ 64
#define N_ 4096
#define D_ 256
#define NS_ 8
#define HID_ 512
#define TOK_ 128
#define NPART_ 32            // N_/TOK_ partial blocks per batch
#define EPS_ 1e-8f
#define SCALE_ 0.0625f
#define LN_EPS_ 1e-5f

typedef _Float16 f16;
typedef __attribute__((ext_vector_type(4))) _Float16 f16x4;
typedef __attribute__((ext_vector_type(8))) _Float16 f16x8;
typedef __attribute__((ext_vector_type(4))) float f32x4;

#define MFMA16(a, b, c) __builtin_amdgcn_mfma_f32_16x16x32_f16(a, b, c, 0, 0, 0)

// ---------------- merged setup: xh LN-cast | WkX | GRU-wT cast | slots | w1/w2 cast ----
__global__ __launch_bounds__(256) void k_setup(
    const float* __restrict__ in, const float* __restrict__ gin,
    const float* __restrict__ bin, f16* __restrict__ xh,
    const float* __restrict__ Wk, float* __restrict__ WkX,
    const float* __restrict__ wi, const float* __restrict__ wh,
    f16* __restrict__ wiTh, f16* __restrict__ whTh,
    const float* __restrict__ noise, const float* __restrict__ mu,
    const float* __restrict__ ls, float* __restrict__ slots,
    const float* __restrict__ w1, const float* __restrict__ w2,
    f16* __restrict__ w1h, f16* __restrict__ w2h) {
  const int blk = blockIdx.x;
  const int t = threadIdx.x;
  if (blk < 65536) {
    const int wave = t >> 6, lane = t & 63;
    const size_t row = (size_t)blk * 4 + wave;
    const float* r = in + row * D_;
    float4 a = *(const float4*)(r + lane * 4);
    float s1 = a.x + a.y + a.z + a.w;
    float s2 = a.x * a.x + a.y * a.y + a.z * a.z + a.w * a.w;
    #pragma unroll
    for (int m = 32; m >= 1; m >>= 1) { s1 += __shfl_xor(s1, m, 64); s2 += __shfl_xor(s2, m, 64); }
    const float mean = s1 * (1.f / D_);
    const float rstd = rsqrtf(s2 * (1.f / D_) - mean * mean + LN_EPS_);
    float4 gg = *(const float4*)(gin + lane * 4);
    float4 bv = *(const float4*)(bin + lane * 4);
    f16x4 o;
    o[0] = (f16)((a.x - mean) * rstd * gg.x + bv.x);
    o[1] = (f16)((a.y - mean) * rstd * gg.y + bv.y);
    o[2] = (f16)((a.z - mean) * rstd * gg.z + bv.z);
    o[3] = (f16)((a.w - mean) * rstd * gg.w + bv.w);
    *(f16x4*)(xh + row * D_ + lane * 4) = o;
  } else if (blk < 65792) {
    const int e = blk - 65536;
    WkX[t * 256 + e] = Wk[e * 256 + t];
  } else if (blk < 66560) {
    const int idx = (blk - 65792) * 256 + t;
    const int o = idx >> 8, d = idx & 255;
    wiTh[d * 768 + o] = (f16)wi[idx];
    whTh[d * 768 + o] = (f16)wh[idx];
  } else if (blk < 67072) {
    const int idx = (blk - 66560) * 256 + t;
    const int d = idx & 255;
    slots[idx] = mu[d] + __expf(ls[d]) * noise[idx];
  } else if (blk < 67584) {
    const int idx = (blk - 67072) * 256 + t;
    w1h[idx] = (f16)w1[idx];
  } else {
    const int idx = (blk - 67584) * 256 + t;
    w2h[idx] = (f16)w2[idx];
  }
}

// ---------------- M[c][e] = SCALE * sum_d Wq[c][d] * WkX[d][e] ----------------
__global__ __launch_bounds__(256) void k_m(const float* __restrict__ Wq,
                                           const float* __restrict__ WkX,
                                           float* __restrict__ M) {
  __shared__ float wq[256];
  const int c = blockIdx.x, e = threadIdx.x;
  wq[e] = Wq[c * 256 + e];
  __syncthreads();
  float a0 = 0.f, a1 = 0.f, a2 = 0.f, a3 = 0.f;
  #pragma unroll 8
  for (int d = 0; d < 256; d += 4) {
    a0 = fmaf(wq[d],     WkX[(d)     * 256 + e], a0);
    a1 = fmaf(wq[d + 1], WkX[(d + 1) * 256 + e], a1);
    a2 = fmaf(wq[d + 2], WkX[(d + 2) * 256 + e], a2);
    a3 = fmaf(wq[d + 3], WkX[(d + 3) * 256 + e], a3);
  }
  M[c * 256 + e] = (a0 + a1 + a2 + a3) * SCALE_;
}

// ---------------- qkh = f16( LN(slots) @ M )  (once, before iter 0) ----------------
__global__ __launch_bounds__(256) void k_qk(const float* __restrict__ slots,
    const float* __restrict__ g, const float* __restrict__ b,
    const float* __restrict__ M, f16* __restrict__ qkh) {
  const int row = blockIdx.x;
  const int t = threadIdx.x;
  __shared__ float sl[256];
  __shared__ float red1[4], red2[4];
  float val = slots[(size_t)row * D_ + t];
  float s1 = val, s2 = val * val;
  #pragma unroll
  for (int m = 32; m >= 1; m >>= 1) { s1 += __shfl_xor(s1, m, 64); s2 += __shfl_xor(s2, m, 64); }
  int wave = t >> 6, lane = t & 63;
  if (lane == 0) { red1[wave] = s1; red2[wave] = s2; }
  __syncthreads();
  s1 = red1[0] + red1[1] + red1[2] + red1[3];
  s2 = red2[0] + red2[1] + red2[2] + red2[3];
  float mean = s1 * (1.f / D_);
  float rstd = rsqrtf(s2 * (1.f / D_) - mean * mean + LN_EPS_);
  sl[t] = (val - mean) * rstd * g[t] + b[t];
  __syncthreads();
  float a0 = 0.f, a1 = 0.f, a2 = 0.f, a3 = 0.f;
  #pragma unroll 8
  for (int d = 0; d < D_; d += 4) {
    a0 = fmaf(sl[d],     M[(d)     * D_ + t], a0);
    a1 = fmaf(sl[d + 1], M[(d + 1) * D_ + t], a1);
    a2 = fmaf(sl[d + 2], M[(d + 2) * D_ + t], a2);
    a3 = fmaf(sl[d + 3], M[(d + 3) * D_ + t], a3);
  }
  qkh[((size_t)(row >> 3) * 16 + (row & 7)) * D_ + t] = (f16)(a0 + a1 + a2 + a3);
}

// ---------------- MFMA attention -> PARTIAL sums (no global atomics) ----------------
// 256 thr, TOK_=128 (round-12 structure). Phase A: 2 N-tiles/wave (MFMA) -> wv_s.
// Phase B: wave -> slots (2w,2w+1); partial u and partial asum stored per block.
__global__ __launch_bounds__(256) void k_attn_upd(
    const f16* __restrict__ xh, const f16* __restrict__ qkh,
    float* __restrict__ urp, float* __restrict__ asp) {
  __shared__ __align__(16) f16 xt[TOK_ * 256];   // 64 KB, chunk-swizzled
  __shared__ __align__(16) f16 qs[16 * 256];     // 8 KB (rows 8-15 pad)
  __shared__ float wv_s[TOK_ * 12];              // 6 KB
  const int b = blockIdx.y;
  const int blkx = blockIdx.x;
  const int jt = blkx * TOK_;
  const int part = b * NPART_ + blkx;            // partial slice index
  const int tid = threadIdx.x;
  const int wave = tid >> 6, lane = tid & 63;

  // stage qs
  {
    const int r = tid >> 4, c0 = (tid & 15) * 2;
    const f16* src = qkh + ((size_t)b * 16 + r) * D_;
    *(f16x8*)&qs[r * 256 + ((c0)     ^ (r & 7)) * 8] = *(const f16x8*)(src + c0 * 8);
    *(f16x8*)&qs[r * 256 + ((c0 + 1) ^ (r & 7)) * 8] = *(const f16x8*)(src + c0 * 8 + 8);
  }
  // stage xt: 16 rounds x 4KB, coalesced loads, swizzled ds_write
  {
    const f16* src = xh + ((size_t)b * N_ + jt) * D_;
    f16x8 v[16];
    #pragma unroll
    for (int i = 0; i < 16; ++i) {
      const int r = i * 8 + (tid >> 5), c = tid & 31;
      v[i] = *(const f16x8*)(src + r * 256 + c * 8);
    }
    #pragma unroll
    for (int i = 0; i < 16; ++i) {
      const int r = i * 8 + (tid >> 5), c = tid & 31;
      *(f16x8*)&xt[r * 256 + (c ^ (r & 7)) * 8] = v[i];
    }
  }
  __syncthreads();

  // phase A: MFMA dots; A-frags (qk) loaded once; 2 N-tiles per wave
  const int kg = lane >> 4;
  f16x8 afr[8];
  {
    const int arow = lane & 15;
    #pragma unroll
    for (int kk = 0; kk < 8; ++kk)
      afr[kk] = *(const f16x8*)&qs[arow * 256 + ((kk * 4 + kg) ^ (arow & 7)) * 8];
  }
  #pragma unroll
  for (int t2 = 0; t2 < 2; ++t2) {
    const int nt = wave * 2 + t2;
    const int tok = nt * 16 + (lane & 15);
    f32x4 acc = {0.f, 0.f, 0.f, 0.f};
    #pragma unroll
    for (int kk = 0; kk < 8; ++kk) {
      f16x8 bf = *(const f16x8*)&xt[tok * 256 + ((kk * 4 + kg) ^ (tok & 7)) * 8];
      acc = MFMA16(afr[kk], bf, acc);
    }
    float o0 = __shfl_xor(acc[0], 16, 64);
    float o1 = __shfl_xor(acc[1], 16, 64);
    float o2 = __shfl_xor(acc[2], 16, 64);
    float o3 = __shfl_xor(acc[3], 16, 64);
    if (lane < 32) {
      float m = fmaxf(fmaxf(fmaxf(acc[0], acc[1]), fmaxf(acc[2], acc[3])),
                      fmaxf(fmaxf(o0, o1), fmaxf(o2, o3)));
      float e0 = __expf(acc[0] - m), e1 = __expf(acc[1] - m);
      float e2 = __expf(acc[2] - m), e3 = __expf(acc[3] - m);
      float sm = e0 + e1 + e2 + e3;
      float so = __shfl_xor(sm, 16, 64);
      float inv = 1.f / (sm + so);
      float4 wv;
      wv.x = e0 * inv + EPS_; wv.y = e1 * inv + EPS_;
      wv.z = e2 * inv + EPS_; wv.w = e3 * inv + EPS_;
      *(float4*)&wv_s[tok * 12 + (lane >> 4) * 4] = wv;
    }
  }
  __syncthreads();

  // phase B: wave -> slots (2w, 2w+1); lane -> d-quad; asum folded in (free)
  {
    const int i0 = wave * 2;
    const int ch0 = lane >> 1, sub = (lane & 1) * 4;
    float a0[4] = {0.f, 0.f, 0.f, 0.f};
    float a1[4] = {0.f, 0.f, 0.f, 0.f};
    float s0 = 0.f, s1 = 0.f;
    #pragma unroll 4
    for (int j = 0; j < TOK_; ++j) {
      f16x4 v = *(const f16x4*)&xt[j * 256 + (ch0 ^ (j & 7)) * 8 + sub];
      float vx = (float)v[0], vy = (float)v[1], vz = (float)v[2], vw = (float)v[3];
      float w0 = wv_s[j * 12 + i0];
      float w1 = wv_s[j * 12 + i0 + 1];
      s0 += w0; s1 += w1;
      a0[0] = fmaf(w0, vx, a0[0]); a0[1] = fmaf(w0, vy, a0[1]);
      a0[2] = fmaf(w0, vz, a0[2]); a0[3] = fmaf(w0, vw, a0[3]);
      a1[0] = fmaf(w1, vx, a1[0]); a1[1] = fmaf(w1, vy, a1[1]);
      a1[2] = fmaf(w1, vz, a1[2]); a1[3] = fmaf(w1, vw, a1[3]);
    }
    float* u0 = urp + ((size_t)part * NS_ + i0) * D_ + lane * 4;
    *(float4*)(u0)      = make_float4(a0[0], a0[1], a0[2], a0[3]);
    *(float4*)(u0 + D_) = make_float4(a1[0], a1[1], a1[2], a1[3]);
    if (lane == 0) {
      asp[part * NS_ + i0]     = s0;
      asp[part * NS_ + i0 + 1] = s1;
    }
  }
}

// ---------------- GRU + LN + MLP + next-qk; reduces 32 partials; f16 weights ----------------
__global__ __launch_bounds__(256) void k_gru_mlp(
    const float* __restrict__ urp, const float* __restrict__ asp,
    const float* __restrict__ slots, const float* __restrict__ Wv,
    const f16* __restrict__ wiTh, const f16* __restrict__ whTh,
    const float* __restrict__ bi, const float* __restrict__ bh,
    const f16* __restrict__ w1h, const float* __restrict__ b1,
    const f16* __restrict__ w2h, const float* __restrict__ b2,
    const float* __restrict__ gf, const float* __restrict__ bf,
    const float* __restrict__ gs, const float* __restrict__ bs,
    const float* __restrict__ M,
    float* __restrict__ out, f16* __restrict__ qkh) {
  const int row = blockIdx.x;
  const int bb = row >> 3, ii = row & 7;
  const int t = threadIdx.x;
  __shared__ float urs[256], xs[256], hs[256], ffs[256], hid[512];
  __shared__ float red1[4], red2[4];
  const int wave = t >> 6, lane = t & 63;
  const float hv = slots[(size_t)row * D_ + t];
  hs[t] = hv;
  // reduce 32 u partials (coalesced over t)
  {
    float usum = 0.f;
    #pragma unroll 8
    for (int p = 0; p < NPART_; ++p)
      usum += urp[((size_t)(bb * NPART_ + p) * NS_ + ii) * D_ + t];
    urs[t] = usum;
  }
  // reduce 32 asum partials via wave 0
  {
    float ap = (t < NPART_) ? asp[(size_t)(bb * NPART_ + t) * NS_ + ii] : 0.f;
    #pragma unroll
    for (int m = 16; m >= 1; m >>= 1) ap += __shfl_xor(ap, m, 64);
    if (t == 0) red1[0] = ap;
  }
  __syncthreads();
  const float asv = red1[0];
  {
    const float ia = 1.f / asv;
    float u0 = 0.f, u1 = 0.f, u2 = 0.f, u3 = 0.f;
    #pragma unroll 8
    for (int e = 0; e < D_; e += 4) {
      u0 = fmaf(urs[e],     Wv[(size_t)(e)     * D_ + t], u0);
      u1 = fmaf(urs[e + 1], Wv[(size_t)(e + 1) * D_ + t], u1);
      u2 = fmaf(urs[e + 2], Wv[(size_t)(e + 2) * D_ + t], u2);
      u3 = fmaf(urs[e + 3], Wv[(size_t)(e + 3) * D_ + t], u3);
    }
    xs[t] = (u0 + u1 + u2 + u3) * ia;
  }
  __syncthreads();
  float gi0 = bi[t], gi1 = bi[D_ + t], gi2 = bi[2 * D_ + t];
  float gh0 = bh[t], gh1 = bh[D_ + t], gh2 = bh[2 * D_ + t];
  #pragma unroll 8
  for (int d = 0; d < D_; ++d) {
    const f16* wid = wiTh + d * 768;
    const f16* whd = whTh + d * 768;
    float xd = xs[d], hd = hs[d];
    gi0 = fmaf(xd, (float)wid[t], gi0);
    gi1 = fmaf(xd, (float)wid[D_ + t], gi1);
    gi2 = fmaf(xd, (float)wid[2 * D_ + t], gi2);
    gh0 = fmaf(hd, (float)whd[t], gh0);
    gh1 = fmaf(hd, (float)whd[D_ + t], gh1);
    gh2 = fmaf(hd, (float)whd[2 * D_ + t], gh2);
  }
  float r = 1.f / (1.f + __expf(-(gi0 + gh0)));
  float z = 1.f / (1.f + __expf(-(gi1 + gh1)));
  float n = tanhf(gi2 + r * gh2);
  float hnew = (1.f - z) * n + z * hv;
  float s1 = hnew, s2 = hnew * hnew;
  #pragma unroll
  for (int m = 32; m >= 1; m >>= 1) { s1 += __shfl_xor(s1, m, 64); s2 += __shfl_xor(s2, m, 64); }
  if (lane == 0) { red1[wave] = s1; red2[wave] = s2; }
  __syncthreads();
  s1 = red1[0] + red1[1] + red1[2] + red1[3];
  s2 = red2[0] + red2[1] + red2[2] + red2[3];
  float mean = s1 * (1.f / D_);
  float rstd = rsqrtf(s2 * (1.f / D_) - mean * mean + LN_EPS_);
  ffs[t] = (hnew - mean) * rstd * gf[t] + bf[t];
  __syncthreads();
  {
    float h1a = b1[t], h2a = b1[D_ + t], h1b = 0.f, h2b = 0.f;
    #pragma unroll 8
    for (int d = 0; d < D_; d += 2) {
      float f0 = ffs[d], f1 = ffs[d + 1];
      h1a = fmaf(f0, (float)w1h[(size_t)(d)     * HID_ + t],      h1a);
      h2a = fmaf(f0, (float)w1h[(size_t)(d)     * HID_ + D_ + t], h2a);
      h1b = fmaf(f1, (float)w1h[(size_t)(d + 1) * HID_ + t],      h1b);
      h2b = fmaf(f1, (float)w1h[(size_t)(d + 1) * HID_ + D_ + t], h2b);
    }
    hid[t] = fmaxf(h1a + h1b, 0.f); hid[D_ + t] = fmaxf(h2a + h2b, 0.f);
  }
  __syncthreads();
  float o;
  {
    float oa = b2[t], ob = 0.f;
    #pragma unroll 8
    for (int d = 0; d < HID_; d += 2) {
      oa = fmaf(hid[d],     (float)w2h[(size_t)(d)     * D_ + t], oa);
      ob = fmaf(hid[d + 1], (float)w2h[(size_t)(d + 1) * D_ + t], ob);
    }
    o = oa + ob + hnew;
  }
  out[(size_t)row * D_ + t] = o;
  // next-iteration qkh = f16( LN_s(new slots) @ M )
  s1 = o; s2 = o * o;
  #pragma unroll
  for (int m = 32; m >= 1; m >>= 1) { s1 += __shfl_xor(s1, m, 64); s2 += __shfl_xor(s2, m, 64); }
  __syncthreads();
  if (lane == 0) { red1[wave] = s1; red2[wave] = s2; }
  __syncthreads();
  s1 = red1[0] + red1[1] + red1[2] + red1[3];
  s2 = red2[0] + red2[1] + red2[2] + red2[3];
  mean = s1 * (1.f / D_);
  rstd = rsqrtf(s2 * (1.f / D_) - mean * mean + LN_EPS_);
  ffs[t] = (o - mean) * rstd * gs[t] + bs[t];
  __syncthreads();
  {
    float a0 = 0.f, a1 = 0.f, a2 = 0.f, a3 = 0.f;
    #pragma unroll 8
    for (int d = 0; d < D_; d += 4) {
      a0 = fmaf(ffs[d],     M[(d)     * D_ + t], a0);
      a1 = fmaf(ffs[d + 1], M[(d + 1) * D_ + t], a1);
      a2 = fmaf(ffs[d + 2], M[(d + 2) * D_ + t], a2);
      a3 = fmaf(ffs[d + 3], M[(d + 3) * D_ + t], a3);
    }
    qkh[((size_t)(row >> 3) * 16 + (row & 7)) * D_ + t] = (f16)(a0 + a1 + a2 + a3);
  }
}

extern "C" void kernel_launch(void* const* d_in, const int* in_sizes, int n_in,
                              void* d_out, int out_size, void* d_ws, size_t ws_size,
                              hipStream_t stream) {
  (void)in_sizes; (void)n_in; (void)out_size; (void)ws_size;
  const float* inputs = (const float*)d_in[0];
  const float* noise  = (const float*)d_in[1];
  const float* mu     = (const float*)d_in[2];
  const float* ls     = (const float*)d_in[3];
  const float* Wq     = (const float*)d_in[4];
  const float* Wk     = (const float*)d_in[5];
  const float* Wv     = (const float*)d_in[6];
  const float* gwi    = (const float*)d_in[7];
  const float* gwh    = (const float*)d_in[8];
  const float* gbi    = (const float*)d_in[9];
  const float* gbh    = (const float*)d_in[10];
  const float* w1     = (const float*)d_in[11];
  const float* b1     = (const float*)d_in[12];
  const float* w2     = (const float*)d_in[13];
  const float* b2     = (const float*)d_in[14];
  const float* gin    = (const float*)d_in[15];
  const float* bin    = (const float*)d_in[16];
  const float* gs     = (const float*)d_in[17];
  const float* bs     = (const float*)d_in[18];
  const float* gff    = (const float*)d_in[19];
  const float* bff    = (const float*)d_in[20];

  // workspace layout
  const size_t KV = (size_t)B_ * N_ * D_;
  f16*   xh    = (f16*)d_ws;                       // 134 MB
  float* slots = (float*)(xh + KV);                // 131072 f32
  f16*   qkh   = (f16*)(slots + 131072);           // 262144 f16
  float* asp   = (float*)(qkh + 262144);           // 16384 f32 (2048 parts x 8)
  float* urp   = asp + 16384;                      // 4.19M f32 (2048 parts x 8 x 256)
  float* WkX   = urp + (size_t)B_ * NPART_ * NS_ * D_;
  float* M     = WkX + 65536;
  f16*   wiTh  = (f16*)(M + 65536);
  f16*   whTh  = wiTh + 196608;
  f16*   w1h   = whTh + 196608;
  f16*   w2h   = w1h + 131072;

  k_setup<<<68096, 256, 0, stream>>>(inputs, gin, bin, xh, Wk, WkX,
                                     gwi, gwh, wiTh, whTh,
                                     noise, mu, ls, slots, w1, w2, w1h, w2h);
  k_m<<<256, 256, 0, stream>>>(Wq, WkX, M);
  k_qk<<<512, 256, 0, stream>>>(slots, gs, bs, M, qkh);
  for (int it = 0; it < 4; ++it) {
    k_attn_upd<<<dim3(NPART_, B_), 256, 0, stream>>>(xh, qkh, urp, asp);
    float* outp = (it == 3) ? (float*)d_out : slots;
    k_gru_mlp<<<512, 256, 0, stream>>>(urp, asp, slots, Wv, wiTh, whTh, gbi, gbh,
                                       w1h, b1, w2h, b2, gff, bff, gs, bs, M,
                                       outp, qkh);
  }
}